// Round 11
// baseline (464.458 us; speedup 1.0000x reference)
//
#include <hip/hip_runtime.h>
#include <math.h>

#define NB 32          // MAX_NODES
#define BATCH 16384
#define STRIDE 36      // A-staging row stride: 16B-aligned, bank-spread

// ws layout (16 B, zeroed by hipMemsetAsync): [0]=bce_sum [1]=mask_sum [2]=phys_sum [3]=unused

__device__ __forceinline__ float groupReduceSum(float v) {
    v += __shfl_xor(v, 1, 64);
    v += __shfl_xor(v, 2, 64);
    v += __shfl_xor(v, 4, 64);
    v += __shfl_xor(v, 8, 64);
    v += __shfl_xor(v, 16, 64);
    return v;
}

// One wave (64 threads) per block; 2 matrices per block (lanes 0-31 -> m=0, 32-63 -> m=1).
__global__ __launch_bounds__(64)
void lap_main(const float* __restrict__ predA, const float* __restrict__ targA,
              const float* __restrict__ nmask, float* __restrict__ out,
              float* __restrict__ ws)
{
    // S: A staging during phases 1-2; then X=[0,32) P=[32,64) D=[64,96) E=[96,128).
    __shared__ __align__(16) float S[2][NB * STRIDE];
    __shared__ __align__(16) float NM[2][NB];

    const int t  = threadIdx.x;       // 0..63
    const int m  = t >> 5;            // matrix within block
    const int j  = t & 31;            // row index within matrix
    const int b0 = blockIdx.x * 2;    // first batch index of this block

    NM[m][j] = nmask[b0 * NB + t];
    __syncthreads();

    // ---- phase 1 (R7-verified): coalesced loads, BCE partials, stage pred into LDS ----
    float accB = 0.f, accM = 0.f;
    const float4* p4 = (const float4*)predA + (size_t)blockIdx.x * 512;
    const float4* t4 = (const float4*)targA + (size_t)blockIdx.x * 512;
    #pragma unroll
    for (int q = 0; q < 8; ++q) {
        const int fi = t + q * 64;
        float4 p  = p4[fi];
        float4 tg = t4[fi];
        const int e  = fi << 2;
        const int mm = e >> 10;
        const int r  = (e >> 5) & 31;
        const int c  = e & 31;
        *(float4*)&S[mm][r * STRIDE + c] = p;
        const float  mr = NM[mm][r];
        const float4 mc = *(const float4*)&NM[mm][c];
        const float bx = -(tg.x * __logf(p.x) + (1.f - tg.x) * __logf(1.f - p.x));
        const float by = -(tg.y * __logf(p.y) + (1.f - tg.y) * __logf(1.f - p.y));
        const float bz = -(tg.z * __logf(p.z) + (1.f - tg.z) * __logf(1.f - p.z));
        const float bw = -(tg.w * __logf(p.w) + (1.f - tg.w) * __logf(1.f - p.w));
        accB += mr * (mc.x * bx + mc.y * by + mc.z * bz + mc.w * bw);
        accM += mr * (mc.x + mc.y + mc.z + mc.w);
    }
    accB = groupReduceSum(accB); accB += __shfl_xor(accB, 32, 64);
    accM = groupReduceSum(accM); accM += __shfl_xor(accM, 32, 64);
    if (t == 0) { atomicAdd(ws + 0, accB); atomicAdd(ws + 1, accM); }  // relaxed, no fence
    __syncthreads();

    // ---- phase 2 (R7-verified): M = (L+L^T)/2 built into registers a[32] ----
    float a[NB];
    #pragma unroll
    for (int i4 = 0; i4 < 8; ++i4) {
        float4 r = *(const float4*)&S[m][j * STRIDE + i4 * 4];
        a[4*i4+0]=r.x; a[4*i4+1]=r.y; a[4*i4+2]=r.z; a[4*i4+3]=r.w;
    }
    float dsum = 0.f;
    #pragma unroll
    for (int i = 0; i < NB; ++i) dsum += a[i];
    {
        const float jitter = 1e-5f + (9e-5f / 31.f) * (float)j;
        const float dval = dsum + jitter - a[j];    // a[j] == pred[j][j]
        #pragma unroll
        for (int i = 0; i < NB; ++i) {
            const float cv = S[m][i * STRIDE + j];  // column j: conflict-free per instr
            const float s  = -0.5f * (a[i] + cv);
            a[i] = (i == j) ? dval : s;
        }
    }
    __syncthreads();                                // staging reads done; S reusable

    float* X = &S[m][0];
    float* P = &S[m][NB];

    // ---- phase 3: Householder (R7 dataflow; cross-lane reduces; rolling pv) ----
    float dcap = 0.f, ecap = 0.f;
    #pragma unroll
    for (int k = 0; k < NB - 2; ++k) {
        const float colk = a[k];
        X[j] = colk;                                // ds_write_b32 bank j: conflict-free
        // sg and x1 computed via cross-lane ops, overlapping the X round-trip:
        const float sg  = groupReduceSum((j > k) ? colk * colk : 0.f);
        const float x1  = __shfl(colk, k + 1, 32);
        __syncthreads();
        float xv[NB];
        #pragma unroll
        for (int i4 = 0; i4 < 8; ++i4) {            // broadcast b128: conflict-free
            if (i4 >= ((k + 1) >> 2)) {
                float4 rr = *(const float4*)&X[i4 * 4];
                xv[4*i4+0]=rr.x; xv[4*i4+1]=rr.y; xv[4*i4+2]=rr.z; xv[4*i4+3]=rr.w;
            }
        }
        const float al = (x1 >= 0.f) ? -sqrtf(sg) : sqrtf(sg);
        const float denom = sg - al * x1;
        const float beta = (denom > 1e-30f) ? __builtin_amdgcn_rcpf(denom) : 0.f;
        const float vj = (j > k) ? (colk - ((j == k + 1) ? al : 0.f)) : 0.f;
        // dot = a_row . x  (8-accumulator tree, then al-fixup)
        float acc[8];
        #pragma unroll
        for (int u = 0; u < 8; ++u) acc[u] = 0.f;
        #pragma unroll
        for (int i = 0; i < NB; ++i) if (i > k) acc[i & 7] += a[i] * xv[i];
        const float dot = ((acc[0] + acc[4]) + (acc[2] + acc[6]))
                        + ((acc[1] + acc[5]) + (acc[3] + acc[7]));
        const float pj = beta * (dot - al * a[k + 1]);
        P[j] = pj;
        const float K = groupReduceSum(vj * pj);    // v.p, overlaps the P round-trip
        __syncthreads();
        const float c  = 0.5f * beta * K;
        const float s2 = pj - 2.f * c * vj;         // = w_j - c*v_j
        if (j >= k) {                               // rows <k frozen (finalized)
            #pragma unroll
            for (int i4 = 0; i4 < 8; ++i4) {        // consume P quad-by-quad (rolling regs)
                if (i4 >= (k >> 2)) {
                    const float4 pq = *(const float4*)&P[i4 * 4];
                    #pragma unroll
                    for (int u = 0; u < 4; ++u) {
                        const int i = 4 * i4 + u;
                        const float pvi = (u == 0) ? pq.x : (u == 1) ? pq.y
                                        : (u == 2) ? pq.z : pq.w;
                        if (i == k) {
                            a[k] -= vj * pvi;       // v_k=0, w_k=p_k (annihilation)
                        } else if (i > k) {
                            const float vi = xv[i] - ((i == k + 1) ? al : 0.f);
                            a[i] -= vj * pvi + s2 * vi;
                        }
                    }
                }
            }
        }
        __syncthreads();                            // P reads done before next X write? X!=P, but next X-read must see new X: barrier placed as in R7
        if (j == k)     dcap = a[k];
        if (j == k + 1) ecap = a[k];
    }
    if (j == NB - 2) dcap = a[NB - 2];
    if (j == NB - 1) { dcap = a[NB - 1]; ecap = a[NB - 2]; }

    // ---- transpose d/e to all lanes (D/E disjoint from X/P) ----
    float* D = &S[m][2 * NB];
    float* E = &S[m][3 * NB];
    D[j] = dcap;
    if (j > 0) E[j - 1] = ecap;
    else       E[NB - 1] = 0.f;
    __syncthreads();
    float d[NB], e2[NB];
    float elast = 0.f;
    #pragma unroll
    for (int i4 = 0; i4 < 8; ++i4) {
        float4 rd = *(const float4*)&D[i4 * 4];
        float4 re = *(const float4*)&E[i4 * 4];
        d[4*i4+0]=rd.x; d[4*i4+1]=rd.y; d[4*i4+2]=rd.z; d[4*i4+3]=rd.w;
        e2[4*i4+0]=re.x*re.x; e2[4*i4+1]=re.y*re.y; e2[4*i4+2]=re.z*re.z; e2[4*i4+3]=re.w*re.w;
        (void)elast;
    }
    // Gershgorin bounds need |e|: recompute from e2 via sqrt-free path — use LDS again
    float lo = 1e30f, hi = -1e30f;
    #pragma unroll
    for (int i = 0; i < NB; ++i) {
        const float ei  = (i < NB - 1) ? sqrtf(e2[i]) : 0.f;
        const float eim = (i > 0) ? sqrtf(e2[i - 1]) : 0.f;
        const float rr = ei + eim;
        lo = fminf(lo, d[i] - rr);
        hi = fmaxf(hi, d[i] + rr);
    }

    // ---- phase 4: Sturm multisection (32 sigmas/round, 3 rounds), rcp-based ----
    for (int round = 0; round < 3; ++round) {
        const float step = (hi - lo) * (1.f / 33.f);
        const float sig = lo + step * (float)(j + 1);
        float q = d[0] - sig;
        int cnt = (q < 0.f);
        #pragma unroll
        for (int i = 1; i < NB; ++i) {
            if (fabsf(q) < 1e-20f) q = (q < 0.f) ? -1e-20f : 1e-20f;
            q = (d[i] - sig) - e2[i - 1] * __builtin_amdgcn_rcpf(q);
            cnt += (q < 0.f);
        }
        const unsigned long long bal = __ballot(cnt >= 2);
        const unsigned int bits = (unsigned int)(bal >> (m * 32));
        const int jstar = (bits == 0u) ? 32 : __builtin_ctz(bits);
        const float nlo = lo + step * (float)jstar;
        const float nhi = lo + step * (float)(jstar + 1);
        lo = nlo; hi = nhi;
    }
    const float lam2 = 0.5f * (lo + hi);

    if (j == 0) out[2 + b0 + m] = lam2;
    const float ph = fmaxf(0.1f - lam2, 0.f);
    const float ph0 = __shfl(ph, 0, 64);
    const float ph1 = __shfl(ph, 32, 64);
    if (t == 0) atomicAdd(ws + 2, ph0 + ph1);       // relaxed; no fence/ticket (R6 lesson)
}

__global__ __launch_bounds__(64)
void lap_final(float* __restrict__ out, const float* __restrict__ ws) {
    if (threadIdx.x == 0) {
        out[0] = ws[0] / fmaxf(ws[1], 1.f);
        out[1] = ws[2] * (1.f / (float)BATCH);
    }
}

extern "C" void kernel_launch(void* const* d_in, const int* in_sizes, int n_in,
                              void* d_out, int out_size, void* d_ws, size_t ws_size,
                              hipStream_t stream) {
    const float* pred = (const float*)d_in[0];
    const float* targ = (const float*)d_in[1];
    const float* nm   = (const float*)d_in[2];
    float* out = (float*)d_out;
    float* ws  = (float*)d_ws;

    (void)hipMemsetAsync(d_ws, 0, 16, stream);
    hipLaunchKernelGGL(lap_main, dim3(BATCH / 2), dim3(64), 0, stream,
                       pred, targ, nm, out, ws);
    hipLaunchKernelGGL(lap_final, dim3(1), dim3(64), 0, stream, out, ws);
}

// Round 12
// 463.851 us; speedup vs baseline: 1.0013x; 1.0013x over previous
//
#include <hip/hip_runtime.h>
#include <math.h>

#define NB 32          // MAX_NODES
#define BATCH 16384
#define STRIDE 36      // A-staging row stride: 16B-aligned, bank-spread

// ws layout (16 B, zeroed by hipMemsetAsync): [0]=bce_sum [1]=mask_sum [2]=phys_sum [3]=unused

__device__ __forceinline__ float groupReduceSum(float v) {
    v += __shfl_xor(v, 1, 64);
    v += __shfl_xor(v, 2, 64);
    v += __shfl_xor(v, 4, 64);
    v += __shfl_xor(v, 8, 64);
    v += __shfl_xor(v, 16, 64);
    return v;
}

// One wave (64 threads) per block; 2 matrices per block (lanes 0-31 -> m=0, 32-63 -> m=1).
__global__ __launch_bounds__(64)
void lap_main(const float* __restrict__ predA, const float* __restrict__ targA,
              const float* __restrict__ nmask, float* __restrict__ out,
              float* __restrict__ ws)
{
    // S: A staging during phases 1-2; then X0=[0,32) X1=[32,64) P=[64,96) D=[96,128) E=[128,160)
    __shared__ __align__(16) float S[2][NB * STRIDE];
    __shared__ __align__(16) float NM[2][NB];

    const int t  = threadIdx.x;       // 0..63
    const int m  = t >> 5;            // matrix within block
    const int j  = t & 31;            // row index within matrix
    const int b0 = blockIdx.x * 2;    // first batch index of this block

    NM[m][j] = nmask[b0 * NB + t];
    __syncthreads();

    // ---- phase 1 (R7-verified): coalesced loads, BCE partials, stage pred into LDS ----
    float accB = 0.f, accM = 0.f;
    const float4* p4 = (const float4*)predA + (size_t)blockIdx.x * 512;
    const float4* t4 = (const float4*)targA + (size_t)blockIdx.x * 512;
    #pragma unroll
    for (int q = 0; q < 8; ++q) {
        const int fi = t + q * 64;
        float4 p  = p4[fi];
        float4 tg = t4[fi];
        const int e  = fi << 2;
        const int mm = e >> 10;
        const int r  = (e >> 5) & 31;
        const int c  = e & 31;
        *(float4*)&S[mm][r * STRIDE + c] = p;
        const float  mr = NM[mm][r];
        const float4 mc = *(const float4*)&NM[mm][c];
        const float bx = -(tg.x * __logf(p.x) + (1.f - tg.x) * __logf(1.f - p.x));
        const float by = -(tg.y * __logf(p.y) + (1.f - tg.y) * __logf(1.f - p.y));
        const float bz = -(tg.z * __logf(p.z) + (1.f - tg.z) * __logf(1.f - p.z));
        const float bw = -(tg.w * __logf(p.w) + (1.f - tg.w) * __logf(1.f - p.w));
        accB += mr * (mc.x * bx + mc.y * by + mc.z * bz + mc.w * bw);
        accM += mr * (mc.x + mc.y + mc.z + mc.w);
    }
    accB = groupReduceSum(accB); accB += __shfl_xor(accB, 32, 64);
    accM = groupReduceSum(accM); accM += __shfl_xor(accM, 32, 64);
    if (t == 0) { atomicAdd(ws + 0, accB); atomicAdd(ws + 1, accM); }  // relaxed, no fence
    __syncthreads();

    // ---- phase 2 (R7-verified): M = (L+L^T)/2 built into registers a[32] ----
    float a[NB];
    #pragma unroll
    for (int i4 = 0; i4 < 8; ++i4) {
        float4 r = *(const float4*)&S[m][j * STRIDE + i4 * 4];
        a[4*i4+0]=r.x; a[4*i4+1]=r.y; a[4*i4+2]=r.z; a[4*i4+3]=r.w;
    }
    {
        float sa[8];
        #pragma unroll
        for (int u = 0; u < 8; ++u) sa[u] = 0.f;
        #pragma unroll
        for (int i = 0; i < NB; ++i) sa[i & 7] += a[i];
        const float dsum = ((sa[0]+sa[4])+(sa[2]+sa[6])) + ((sa[1]+sa[5])+(sa[3]+sa[7]));
        const float jitter = 1e-5f + (9e-5f / 31.f) * (float)j;
        const float dval = dsum + jitter - a[j];    // a[j] == pred[j][j]
        #pragma unroll
        for (int i = 0; i < NB; ++i) {
            const float cv = S[m][i * STRIDE + j];  // column j: conflict-free per instr
            const float s  = -0.5f * (a[i] + cv);
            a[i] = (i == j) ? dval : s;
        }
    }
    __syncthreads();                                // staging reads done; S reusable

    float* X0 = &S[m][0];
    float* X1 = &S[m][NB];
    float* P  = &S[m][2 * NB];

    // prologue: publish column 0
    X0[j] = a[0];
    __syncthreads();

    // ---- phase 3: Householder; zero cross-lane reduces; double-buffered X; 2 barriers ----
    float dcap = 0.f, ecap = 0.f;
    #pragma unroll
    for (int k = 0; k < NB - 2; ++k) {
        float* Xc = (k & 1) ? X1 : X0;
        float* Xn = (k & 1) ? X0 : X1;
        // read column k (broadcast b128: conflict-free)
        float xv[NB];
        #pragma unroll
        for (int i4 = 0; i4 < 8; ++i4) {
            if (i4 >= ((k + 1) >> 2)) {
                float4 rr = *(const float4*)&Xc[i4 * 4];
                xv[4*i4+0]=rr.x; xv[4*i4+1]=rr.y; xv[4*i4+2]=rr.z; xv[4*i4+3]=rr.w;
            }
        }
        // sg and dot lane-locally, 8-acc trees (independent -> co-issue)
        float sa[8], da[8];
        #pragma unroll
        for (int u = 0; u < 8; ++u) { sa[u] = 0.f; da[u] = 0.f; }
        #pragma unroll
        for (int i = 0; i < NB; ++i) if (i > k) {
            sa[i & 7] += xv[i] * xv[i];
            da[i & 7] += a[i]  * xv[i];
        }
        const float sg  = ((sa[0]+sa[4])+(sa[2]+sa[6])) + ((sa[1]+sa[5])+(sa[3]+sa[7]));
        const float dot = ((da[0]+da[4])+(da[2]+da[6])) + ((da[1]+da[5])+(da[3]+da[7]));
        const float x1 = xv[k + 1];
        const float al = (x1 >= 0.f) ? -sqrtf(sg) : sqrtf(sg);
        const float denom = sg - al * x1;
        const float beta = (denom > 1e-30f) ? __builtin_amdgcn_rcpf(denom) : 0.f;
        const float vj = (j > k) ? (a[k] - ((j == k + 1) ? al : 0.f)) : 0.f;
        const float pj = beta * (dot - al * a[k + 1]);
        P[j] = pj;
        __syncthreads();
        // K = v.p lane-locally: rolling pass over P quads
        float ka[8];
        #pragma unroll
        for (int u = 0; u < 8; ++u) ka[u] = 0.f;
        #pragma unroll
        for (int i4 = 0; i4 < 8; ++i4) {
            if (i4 >= (k >> 2)) {
                const float4 pq = *(const float4*)&P[i4 * 4];
                #pragma unroll
                for (int u = 0; u < 4; ++u) {
                    const int i = 4 * i4 + u;
                    if (i > k) {
                        const float pvi = (u == 0) ? pq.x : (u == 1) ? pq.y
                                        : (u == 2) ? pq.z : pq.w;
                        ka[i & 7] += (xv[i] - ((i == k + 1) ? al : 0.f)) * pvi;
                    }
                }
            }
        }
        const float K  = ((ka[0]+ka[4])+(ka[2]+ka[6])) + ((ka[1]+ka[5])+(ka[3]+ka[7]));
        const float c  = 0.5f * beta * K;
        const float s2 = pj - 2.f * c * vj;         // = w_j - c*v_j
        if (j >= k) {                               // rows <k frozen (finalized)
            #pragma unroll
            for (int i4 = 0; i4 < 8; ++i4) {        // consume P quad-by-quad (rolling)
                if (i4 >= (k >> 2)) {
                    const float4 pq = *(const float4*)&P[i4 * 4];
                    #pragma unroll
                    for (int u = 0; u < 4; ++u) {
                        const int i = 4 * i4 + u;
                        const float pvi = (u == 0) ? pq.x : (u == 1) ? pq.y
                                        : (u == 2) ? pq.z : pq.w;
                        if (i == k) {
                            a[k] -= vj * pvi;       // v_k=0, w_k=p_k (annihilation)
                        } else if (i > k) {
                            const float vi = xv[i] - ((i == k + 1) ? al : 0.f);
                            a[i] -= vj * pvi + s2 * vi;
                        }
                    }
                }
            }
        }
        Xn[j] = a[k + 1];                           // publish next column (disjoint buffer)
        __syncthreads();                            // Xn visible; all P reads done
        if (j == k)     dcap = a[k];
        if (j == k + 1) ecap = a[k];
    }
    if (j == NB - 2) dcap = a[NB - 2];
    if (j == NB - 1) { dcap = a[NB - 1]; ecap = a[NB - 2]; }

    // ---- transpose d/e to all lanes (D/E disjoint from X/P) ----
    float* D = &S[m][3 * NB];
    float* E = &S[m][4 * NB];
    D[j] = dcap;
    if (j > 0) E[j - 1] = ecap;
    else       E[NB - 1] = 0.f;
    __syncthreads();
    float d[NB], e2[NB];
    float lo = 1e30f, hi = -1e30f;
    {
        float ea[NB];
        #pragma unroll
        for (int i4 = 0; i4 < 8; ++i4) {
            float4 rd = *(const float4*)&D[i4 * 4];
            float4 re = *(const float4*)&E[i4 * 4];
            d[4*i4+0]=rd.x; d[4*i4+1]=rd.y; d[4*i4+2]=rd.z; d[4*i4+3]=rd.w;
            ea[4*i4+0]=fabsf(re.x); ea[4*i4+1]=fabsf(re.y);
            ea[4*i4+2]=fabsf(re.z); ea[4*i4+3]=fabsf(re.w);
            e2[4*i4+0]=re.x*re.x; e2[4*i4+1]=re.y*re.y;
            e2[4*i4+2]=re.z*re.z; e2[4*i4+3]=re.w*re.w;
        }
        #pragma unroll
        for (int i = 0; i < NB; ++i) {
            const float rr = ((i > 0) ? ea[i - 1] : 0.f) + ((i < NB - 1) ? ea[i] : 0.f);
            lo = fminf(lo, d[i] - rr);
            hi = fmaxf(hi, d[i] + rr);
        }
    }

    // ---- phase 4: Sturm multisection (32 sigmas/round, 3 rounds), rcp-based ----
    for (int round = 0; round < 3; ++round) {
        const float step = (hi - lo) * (1.f / 33.f);
        const float sig = lo + step * (float)(j + 1);
        float q = d[0] - sig;
        int cnt = (q < 0.f);
        #pragma unroll
        for (int i = 1; i < NB; ++i) {
            if (fabsf(q) < 1e-20f) q = (q < 0.f) ? -1e-20f : 1e-20f;
            q = (d[i] - sig) - e2[i - 1] * __builtin_amdgcn_rcpf(q);
            cnt += (q < 0.f);
        }
        const unsigned long long bal = __ballot(cnt >= 2);
        const unsigned int bits = (unsigned int)(bal >> (m * 32));
        const int jstar = (bits == 0u) ? 32 : __builtin_ctz(bits);
        const float nlo = lo + step * (float)jstar;
        const float nhi = lo + step * (float)(jstar + 1);
        lo = nlo; hi = nhi;
    }
    const float lam2 = 0.5f * (lo + hi);

    if (j == 0) out[2 + b0 + m] = lam2;
    const float ph = fmaxf(0.1f - lam2, 0.f);
    const float ph0 = __shfl(ph, 0, 64);
    const float ph1 = __shfl(ph, 32, 64);
    if (t == 0) atomicAdd(ws + 2, ph0 + ph1);       // relaxed; no fence/ticket (R6 lesson)
}

__global__ __launch_bounds__(64)
void lap_final(float* __restrict__ out, const float* __restrict__ ws) {
    if (threadIdx.x == 0) {
        out[0] = ws[0] / fmaxf(ws[1], 1.f);
        out[1] = ws[2] * (1.f / (float)BATCH);
    }
}

extern "C" void kernel_launch(void* const* d_in, const int* in_sizes, int n_in,
                              void* d_out, int out_size, void* d_ws, size_t ws_size,
                              hipStream_t stream) {
    const float* pred = (const float*)d_in[0];
    const float* targ = (const float*)d_in[1];
    const float* nm   = (const float*)d_in[2];
    float* out = (float*)d_out;
    float* ws  = (float*)d_ws;

    (void)hipMemsetAsync(d_ws, 0, 16, stream);
    hipLaunchKernelGGL(lap_main, dim3(BATCH / 2), dim3(64), 0, stream,
                       pred, targ, nm, out, ws);
    hipLaunchKernelGGL(lap_final, dim3(1), dim3(64), 0, stream, out, ws);
}